// Round 6
// baseline (172.325 us; speedup 1.0000x reference)
//
#include <hip/hip_runtime.h>

// ActivatedAttention: out = transpose(GroupNorm( relu(rope(Q)) @ [relu(rope(K))^T @ relu(V)] )).
// B=4, T=2048, D=1024. y = Q @ (K^T V)  (no softmax -> associativity).
// All GEMMs hi-only bf16 (absmax 0.0234 vs threshold 0.0728, bench-validated).
// gemm1: 256x128 block tile, 4 waves of 128x64 (24 ds_read_b128 : 64 MFMA per K-step ->
// MFMA-bound), fused table-rope/relu/bf16 epilogue via LDS f32 tile in 2 m-chunks.
// gemm2/3: 128x128 core (keeps 256/512-block grids -> full CU coverage).
// Staging: global_load_lds width=16, linear LDS dest, XOR-swizzled global source +
// swizzled ds_read (slot ^= row&7 on [rows][64] bf16 buffers) -> conflict-free.

typedef unsigned short u16;
typedef __attribute__((ext_vector_type(8))) unsigned short u16x8;
typedef __attribute__((ext_vector_type(4))) float fx4;
typedef __attribute__((ext_vector_type(8))) __bf16 bfx8;

#define TP 129  // epilogue f32 tile pitch

__device__ __forceinline__ u16 f2bh(float v) {  // f32 -> bf16 RNE
  unsigned u = __float_as_uint(v);
  return (u16)((u + 0x7FFFu + ((u >> 16) & 1u)) >> 16);
}
__device__ __forceinline__ fx4 mfma16(bfx8 a, bfx8 b, fx4 c) {
  return __builtin_amdgcn_mfma_f32_16x16x32_bf16(a, b, c, 0, 0, 0);
}

__device__ __forceinline__ void gload16(const u16* g, u16* l) {
  __builtin_amdgcn_global_load_lds(
      (const __attribute__((address_space(1))) unsigned int*)(const void*)g,
      (__attribute__((address_space(3))) unsigned int*)(void*)l, 16, 0, 0);
}

// Swizzled LDS read: buffer is [rows][8 slots of 16B]; logical slot q of row r
// lives at physical slot q ^ (r&7).
__device__ __forceinline__ bfx8 ldsw(const u16* lds, int row, int slot) {
  const char* p = (const char*)lds + row * 128 + ((slot ^ (row & 7)) << 4);
  return __builtin_bit_cast(bfx8, *reinterpret_cast<const u16x8*>(p));
}

// Stage NCH*64 16B-chunks: rows rowBase..+(NCH*32-1), cols k0..k0+63. Linear LDS dest,
// pre-swizzled global source so the read-side XOR matches (both-sides-or-neither).
template <int NCH>
__device__ __forceinline__ void stageN(const u16* __restrict__ A,
                                       size_t rowBase, int stride, int k0,
                                       u16* lds, int w, int lane) {
#pragma unroll
  for (int i = 0; i < NCH; ++i) {
    int c = ((w * NCH + i) << 6) + lane;
    int r = c >> 3, s = c & 7;
    int t = s ^ (r & 7);
    const u16* src = A + (rowBase + (size_t)r) * (size_t)stride + k0 + (t << 3);
    gload16(src, lds + ((w * NCH + i) << 9));
  }
}

// ---- hi-only 128x128 GEMM core, BK=64, 4 waves of 64x64. (used by gemm2/gemm3)
__device__ inline void gemm_core_hi64(const u16* __restrict__ A, size_t aBase, int aStr,
                                      const u16* __restrict__ B, size_t bBase, int bStr, int K,
                                      u16* sA, u16* sB, fx4 acc[4][4], int w, int lane) {
  int wm = (w >> 1) * 64, wn = (w & 1) * 64;
  int lr = lane & 15, lk = lane >> 4;
  for (int k0 = 0; k0 < K; k0 += 64) {
    __syncthreads();
    stageN<4>(A, aBase, aStr, k0, sA, w, lane);
    stageN<4>(B, bBase, bStr, k0, sB, w, lane);
    __syncthreads();
    bfx8 a[8], b[8];
#pragma unroll
    for (int h = 0; h < 2; ++h)
#pragma unroll
      for (int i = 0; i < 4; ++i) {
        a[h * 4 + i] = ldsw(sA, wm + i * 16 + lr, h * 4 + lk);
        b[h * 4 + i] = ldsw(sB, wn + i * 16 + lr, h * 4 + lk);
      }
#pragma unroll
    for (int h = 0; h < 2; ++h)
#pragma unroll
      for (int mi = 0; mi < 4; ++mi)
#pragma unroll
        for (int ni = 0; ni < 4; ++ni)
          acc[mi][ni] = mfma16(a[h * 4 + mi], b[h * 4 + ni], acc[mi][ni]);
  }
}

// ---- K0a: rope cos/sin tables. y=0: tabTI[t][i]; y=1: tabIT[i][t]. float2(cos,sin).
__global__ void k_ropetab(float2* __restrict__ tabTI, float2* __restrict__ tabIT) {
  int idx = blockIdx.x * 256 + threadIdx.x;  // 1M entries
  int t, i;
  if (blockIdx.y == 0) {
    t = idx >> 9;
    i = idx & 511;
  } else {
    i = idx >> 11;
    t = idx & 2047;
  }
  float invf = exp2f(-(float)i * (13.287712379549449f / 512.f));  // 10000^(-i/512)
  float ang = (float)t * invf, s, c;
  sincosf(ang, &s, &c);
  if (blockIdx.y == 0)
    tabTI[idx] = make_float2(c, s);
  else
    tabIT[idx] = make_float2(c, s);
}

// ---- K0b: transpose W (1024x3072 f32) -> WT[3072][1024] bf16
__global__ void k_transW(const float* __restrict__ W, u16* __restrict__ WTh) {
  __shared__ float tile[32][33];
  int n0 = blockIdx.x * 32, k0 = blockIdx.y * 32;
  int tid = threadIdx.x;
  int c = tid & 31, r4 = tid >> 5;
#pragma unroll
  for (int it = 0; it < 4; ++it) {
    int r = r4 + it * 8;
    tile[r][c] = W[(size_t)(k0 + r) * 3072 + n0 + c];
  }
  __syncthreads();
#pragma unroll
  for (int it = 0; it < 4; ++it) {
    int r = r4 + it * 8;
    WTh[(size_t)(n0 + r) * 1024 + k0 + c] = f2bh(tile[c][r]);
  }
}

// ---- K0c: cast x -> bf16 (8 elems/thread)
__global__ void k_castX(const float* __restrict__ x, u16* __restrict__ xh) {
  size_t i = ((size_t)blockIdx.x * 256 + threadIdx.x) * 8;
  fx4 v0 = *reinterpret_cast<const fx4*>(x + i);
  fx4 v1 = *reinterpret_cast<const fx4*>(x + i + 4);
  u16x8 h;
#pragma unroll
  for (int j = 0; j < 4; ++j) {
    h[j] = f2bh(v0[j]);
    h[4 + j] = f2bh(v1[j]);
  }
  *reinterpret_cast<u16x8*>(xh + i) = h;
}

// ---- G1 fused: relu(rope(x@W+b)) -> Qh row-major, Kth/Vth transposed [B][D][T].
// 256x128 tile, 4 waves of 128x64.
__global__ __launch_bounds__(256, 2) void k_gemm1f(const u16* __restrict__ xh,
                                                   const u16* __restrict__ WTh,
                                                   const float* __restrict__ b_in,
                                                   const float2* __restrict__ tabTI,
                                                   const float2* __restrict__ tabIT,
                                                   u16* __restrict__ Qh, u16* __restrict__ Kth,
                                                   u16* __restrict__ Vth) {
  __shared__ __align__(16) float shbuf[128 * TP];  // 66KB; staging (48KB) aliases front
  u16* sA = (u16*)shbuf;          // 256 x 64 bf16 = 32KB
  u16* sB = sA + 256 * 64;        // 128 x 64 bf16 = 16KB
  // XCD-chunked swizzle: 768 blocks = 8 XCD x (4 mt x 24 nt), mt-fastest.
  // Per-XCD A slice = 4 x 256 rows x 2KB = 2MB (L2-resident).
  int bid = blockIdx.x;
  int xcd = bid & 7, idx = bid >> 3;
  int mt = (xcd << 2) + (idx & 3), nt = idx >> 2;
  int m0 = mt << 8, n0 = nt << 7;
  int tid = threadIdx.x, lane = tid & 63, w = tid >> 6;
  int wm = (w >> 1) * 128, wn = (w & 1) * 64;
  int lr = lane & 15, lk = lane >> 4;
  fx4 acc[8][4];
#pragma unroll
  for (int i = 0; i < 8; ++i)
#pragma unroll
    for (int j = 0; j < 4; ++j) acc[i][j] = fx4{0.f, 0.f, 0.f, 0.f};

  for (int k0 = 0; k0 < 1024; k0 += 64) {
    __syncthreads();
    stageN<8>(xh, (size_t)m0, 1024, k0, sA, w, lane);
    stageN<4>(WTh, (size_t)n0, 1024, k0, sB, w, lane);
    __syncthreads();
#pragma unroll
    for (int h = 0; h < 2; ++h) {
      bfx8 b[4];
#pragma unroll
      for (int ni = 0; ni < 4; ++ni) b[ni] = ldsw(sB, wn + ni * 16 + lr, h * 4 + lk);
#pragma unroll
      for (int mi = 0; mi < 8; ++mi) {
        bfx8 a = ldsw(sA, wm + mi * 16 + lr, h * 4 + lk);
#pragma unroll
        for (int ni = 0; ni < 4; ++ni) acc[mi][ni] = mfma16(a, b[ni], acc[mi][ni]);
      }
    }
  }

  // ---- Epilogue in 2 m-chunks of 128 rows through the f32 LDS tile.
  int part = n0 >> 10;  // 0=Q, 1=K, 2=V (uniform per block)
  int d0 = n0 - (part << 10);
  int bb = m0 >> 11;
  float bv[4];
#pragma unroll
  for (int ni = 0; ni < 4; ++ni) bv[ni] = b_in[n0 + wn + ni * 16 + lr];
  int rl0 = tid >> 4;       // store row within chunk (per pass +16)
  int cc = (tid & 15) * 8;  // 8-elem column chunk

#pragma unroll
  for (int ch = 0; ch < 2; ++ch) {
    __syncthreads();  // staging/compute or previous-chunk reads complete
    if ((w >> 1) == ch) {
      // write this wave's acc (+bias) into tile; Q: [m][n], K/V: [n][m]
#pragma unroll
      for (int mi = 0; mi < 8; ++mi)
#pragma unroll
        for (int ni = 0; ni < 4; ++ni)
#pragma unroll
          for (int r = 0; r < 4; ++r) {
            float v = acc[mi][ni][r] + bv[ni];
            int ml = mi * 16 + lk * 4 + r;       // m-local within chunk
            int nl = wn + ni * 16 + lr;          // n-local
            if (part == 0)
              shbuf[ml * TP + nl] = v;
            else
              shbuf[nl * TP + ml] = v;
          }
    }
    __syncthreads();
    int tb = (m0 & 2047) + (ch << 7);
    if (part == 2) {  // V: relu, store [d][t]
#pragma unroll
      for (int pass = 0; pass < 8; ++pass) {
        int rl = rl0 + pass * 16;
        u16x8 o;
#pragma unroll
        for (int j = 0; j < 8; ++j) o[j] = f2bh(fmaxf(shbuf[rl * TP + cc + j], 0.f));
        *reinterpret_cast<u16x8*>(Vth + (((size_t)(bb << 10) + d0 + rl) << 11) + tb + cc) = o;
      }
    } else if (part == 1) {  // K: rope rows (d, d^1) + relu, store [d][t]
#pragma unroll
      for (int pass = 0; pass < 8; ++pass) {
        int rl = rl0 + pass * 16;
        int d = d0 + rl;
        const float2* tp = tabIT + ((size_t)(d >> 1) << 11) + tb + cc;
        const float* e = shbuf + (rl & ~1) * TP + cc;
        const float* oo = shbuf + (rl | 1) * TP + cc;
        int isOdd = d & 1;
        u16x8 o;
#pragma unroll
        for (int j = 0; j < 8; ++j) {
          float2 cs = tp[j];
          float x1 = e[j], x2 = oo[j];
          float v = isOdd ? (x1 * cs.y + x2 * cs.x) : (x1 * cs.x - x2 * cs.y);
          o[j] = f2bh(fmaxf(v, 0.f));
        }
        *reinterpret_cast<u16x8*>(Kth + (((size_t)(bb << 10) + d) << 11) + tb + cc) = o;
      }
    } else {  // Q: rope along row + relu, store [m][d]
#pragma unroll
      for (int pass = 0; pass < 8; ++pass) {
        int rl = rl0 + pass * 16;
        int m = m0 + (ch << 7) + rl, t = m & 2047;
        const float2* tp = tabTI + ((size_t)t << 9) + ((d0 + cc) >> 1);
        const float* row = shbuf + rl * TP + cc;
        u16x8 o;
#pragma unroll
        for (int jp = 0; jp < 4; ++jp) {
          float x1 = row[2 * jp], x2 = row[2 * jp + 1];
          float2 cs = tp[jp];
          o[2 * jp] = f2bh(fmaxf(x1 * cs.x - x2 * cs.y, 0.f));
          o[2 * jp + 1] = f2bh(fmaxf(x1 * cs.y + x2 * cs.x, 0.f));
        }
        *reinterpret_cast<u16x8*>(Qh + ((size_t)m << 10) + d0 + cc) = o;
      }
    }
  }
}

// ---- G2: KtVT[b][n][m] = (K^T V)[m][n], bf16 out
__global__ __launch_bounds__(256) void k_gemm2(const u16* __restrict__ Kth, const u16* __restrict__ Vth,
                                               u16* __restrict__ KtVTh) {
  __shared__ u16 sA[128 * 64], sB[128 * 64];
  fx4 acc[4][4];
#pragma unroll
  for (int i = 0; i < 4; ++i)
#pragma unroll
    for (int j = 0; j < 4; ++j) acc[i][j] = fx4{0.f, 0.f, 0.f, 0.f};
  int b = blockIdx.z;
  int m0 = blockIdx.x << 7, n0 = blockIdx.y << 7;
  int tid = threadIdx.x, lane = tid & 63, w = tid >> 6;
  const u16* Ab = Kth + ((size_t)b << 21);
  const u16* Bb = Vth + ((size_t)b << 21);
  gemm_core_hi64(Ab, (size_t)m0, 2048, Bb, (size_t)n0, 2048, 2048, sA, sB, acc, w, lane);
  int wm = (w >> 1) * 64, wn = (w & 1) * 64, lr = lane & 15, lk = lane >> 4;
#pragma unroll
  for (int mi = 0; mi < 4; ++mi)
#pragma unroll
    for (int ni = 0; ni < 4; ++ni)
#pragma unroll
      for (int r = 0; r < 4; ++r) {
        int m = m0 + wm + mi * 16 + lk * 4 + r;
        int n = n0 + wn + ni * 16 + lr;
        KtVTh[((size_t)b << 20) + ((size_t)n << 10) + m] = f2bh(acc[mi][ni][r]);
      }
}

// ---- G3 fused: y = Q @ KtV, then GroupNorm(32-ch groups) + transposed store out[b][d][t].
__global__ __launch_bounds__(256) void k_gemm3g(const u16* __restrict__ Qh, const u16* __restrict__ KtVTh,
                                                const float* __restrict__ gw, const float* __restrict__ gb,
                                                float* __restrict__ out) {
  __shared__ u16 sA[128 * 64], sB[128 * 64];
  fx4 acc[4][4];
#pragma unroll
  for (int i = 0; i < 4; ++i)
#pragma unroll
    for (int j = 0; j < 4; ++j) acc[i][j] = fx4{0.f, 0.f, 0.f, 0.f};
  int b = blockIdx.z;
  int m0 = blockIdx.x << 7, n0 = blockIdx.y << 7;
  int tid = threadIdx.x, lane = tid & 63, w = tid >> 6;
  gemm_core_hi64(Qh, (size_t)(b * 2048 + m0), 1024, KtVTh + ((size_t)b << 20), (size_t)n0, 1024, 1024,
                 sA, sB, acc, w, lane);
  int wm = (w >> 1) * 64, wn = (w & 1) * 64, lr = lane & 15, lk = lane >> 4;
  float wv[4], bvv[4];
#pragma unroll
  for (int ni = 0; ni < 4; ++ni) {
    int n = n0 + wn + ni * 16 + lr;
    wv[ni] = gw[n];
    bvv[ni] = gb[n];
  }
#pragma unroll
  for (int mi = 0; mi < 4; ++mi) {
    fx4 o0, o1, o2, o3;
#pragma unroll
    for (int r = 0; r < 4; ++r) {
      float v0 = acc[mi][0][r], v1 = acc[mi][1][r], v2 = acc[mi][2][r], v3 = acc[mi][3][r];
      float sA2 = v0 + v1, sB2 = v2 + v3;
#pragma unroll
      for (int mk = 1; mk <= 8; mk <<= 1) {
        sA2 += __shfl_xor(sA2, mk);
        sB2 += __shfl_xor(sB2, mk);
      }
      float mA = sA2 * (1.f / 32.f), mB = sB2 * (1.f / 32.f);
      float dA = (v0 - mA) * (v0 - mA) + (v1 - mA) * (v1 - mA);
      float dB = (v2 - mB) * (v2 - mB) + (v3 - mB) * (v3 - mB);
#pragma unroll
      for (int mk = 1; mk <= 8; mk <<= 1) {
        dA += __shfl_xor(dA, mk);
        dB += __shfl_xor(dB, mk);
      }
      float rA = rsqrtf(dA * (1.f / 32.f) + 1e-5f);
      float rB = rsqrtf(dB * (1.f / 32.f) + 1e-5f);
      o0[r] = (v0 - mA) * rA * wv[0] + bvv[0];
      o1[r] = (v1 - mA) * rA * wv[1] + bvv[1];
      o2[r] = (v2 - mB) * rB * wv[2] + bvv[2];
      o3[r] = (v3 - mB) * rB * wv[3] + bvv[3];
    }
    int mbase = m0 + wm + mi * 16 + lk * 4;  // t index, 16B-aligned
#pragma unroll
    for (int ni = 0; ni < 4; ++ni) {
      int n = n0 + wn + ni * 16 + lr;
      fx4 ov = (ni == 0) ? o0 : (ni == 1) ? o1 : (ni == 2) ? o2 : o3;
      *reinterpret_cast<fx4*>(out + (((size_t)(b << 10) + n) << 11) + mbase) = ov;
    }
  }
}

extern "C" void kernel_launch(void* const* d_in, const int* in_sizes, int n_in,
                              void* d_out, int out_size, void* d_ws, size_t ws_size,
                              hipStream_t stream) {
  const float* x = (const float*)d_in[0];
  const float* W = (const float*)d_in[1];
  const float* b_in = (const float*)d_in[2];
  const float* gnw = (const float*)d_in[3];
  const float* gnb = (const float*)d_in[4];
  float* out = (float*)d_out;
  char* ws = (char*)d_ws;

  // Workspace (bytes): xh@0(16M) WTh@16M(6M) Qh@22M(16M) Kth@38M(16M) Vth@54M(16M)
  // KtVTh@70M(8M) tabTI@78M(8M) tabIT@86M(8M). Total ~94MB.
  u16* xh = (u16*)(ws + 0);
  u16* WTh = (u16*)(ws + 16777216);
  u16* Qh = (u16*)(ws + 23068672);
  u16* Kth = (u16*)(ws + 39845888);
  u16* Vth = (u16*)(ws + 56623104);
  u16* KtVTh = (u16*)(ws + 73400320);
  float2* tabTI = (float2*)(ws + 81788928);
  float2* tabIT = (float2*)(ws + 90177536);

  k_ropetab<<<dim3(4096, 2), 256, 0, stream>>>(tabTI, tabIT);
  k_transW<<<dim3(96, 32), 256, 0, stream>>>(W, WTh);
  k_castX<<<4096, 256, 0, stream>>>(x, xh);
  k_gemm1f<<<768, 256, 0, stream>>>(xh, WTh, b_in, tabTI, tabIT, Qh, Kth, Vth);
  k_gemm2<<<dim3(8, 8, 4), 256, 0, stream>>>(Kth, Vth, KtVTh);
  k_gemm3g<<<dim3(16, 8, 4), 256, 0, stream>>>(Qh, KtVTh, gnw, gnb, out);
}

// Round 7
// 146.113 us; speedup vs baseline: 1.1794x; 1.1794x over previous
//
#include <hip/hip_runtime.h>

// ActivatedAttention: out = transpose(GroupNorm( relu(rope(Q)) @ [relu(rope(K))^T @ relu(V)] )).
// B=4, T=2048, D=1024. y = Q @ (K^T V)  (no softmax -> associativity).
// All GEMMs hi-only bf16 (absmax 0.0234 vs threshold 0.0728, bench-validated).
// Core: 128x128 tile, 4 waves, BK=64, DOUBLE-BUFFERED global_load_lds staging with
// counted vmcnt(8) (never drained in-loop) + raw s_barriers: load latency for tile t+1
// hides under ds_read+MFMA of tile t. Second barrier protects WAR on the restaged buffer.
// gemm1 fuses table-rope/relu/bf16 epilogue; gemm3 fuses GroupNorm + transposed store.
// Staging swizzle: linear LDS dest, XOR-swizzled global source + swizzled ds_read
// (slot ^= row&7 on [128][64] bf16 buffers) -> conflict-free.

typedef unsigned short u16;
typedef __attribute__((ext_vector_type(8))) unsigned short u16x8;
typedef __attribute__((ext_vector_type(4))) float fx4;
typedef __attribute__((ext_vector_type(8))) __bf16 bfx8;

#define TP 129  // epilogue f32 tile pitch

__device__ __forceinline__ u16 f2bh(float v) {  // f32 -> bf16 RNE
  unsigned u = __float_as_uint(v);
  return (u16)((u + 0x7FFFu + ((u >> 16) & 1u)) >> 16);
}
__device__ __forceinline__ fx4 mfma16(bfx8 a, bfx8 b, fx4 c) {
  return __builtin_amdgcn_mfma_f32_16x16x32_bf16(a, b, c, 0, 0, 0);
}

__device__ __forceinline__ void gload16(const u16* g, u16* l) {
  __builtin_amdgcn_global_load_lds(
      (const __attribute__((address_space(1))) unsigned int*)(const void*)g,
      (__attribute__((address_space(3))) unsigned int*)(void*)l, 16, 0, 0);
}

// Swizzled LDS read: buffer is [128 rows][8 slots of 16B]; logical slot q of row r
// lives at physical slot q ^ (r&7).
__device__ __forceinline__ bfx8 ldsw(const u16* lds, int row, int slot) {
  const char* p = (const char*)lds + row * 128 + ((slot ^ (row & 7)) << 4);
  return __builtin_bit_cast(bfx8, *reinterpret_cast<const u16x8*>(p));
}

// Stage 128 rows x 64 cols (4 chunks/thread). Linear LDS dest, pre-swizzled global
// source so the read-side XOR matches (both-sides-or-neither).
__device__ __forceinline__ void stage4(const u16* __restrict__ A,
                                       size_t rowBase, int stride, int k0,
                                       u16* lds, int w, int lane) {
#pragma unroll
  for (int i = 0; i < 4; ++i) {
    int c = ((w * 4 + i) << 6) + lane;
    int r = c >> 3, s = c & 7;
    int t = s ^ (r & 7);
    const u16* src = A + (rowBase + (size_t)r) * (size_t)stride + k0 + (t << 3);
    gload16(src, lds + ((w * 4 + i) << 9));
  }
}

// ---- Pipelined hi-only 128x128 GEMM core, BK=64, double-buffered staging.
// Per K-step/wave: 8 gload_lds (next tile) -> vmcnt(8) -> barrier -> 16 ds_read_b128
// -> lgkmcnt(0) -> barrier (WAR) -> 32 MFMA.
__device__ inline void gemm_core_pipe(const u16* __restrict__ A, size_t aBase, int aStr,
                                      const u16* __restrict__ B, size_t bBase, int bStr, int K,
                                      u16* sA0, u16* sB0, u16* sA1, u16* sB1,
                                      fx4 acc[4][4], int w, int lane) {
  int wm = (w >> 1) * 64, wn = (w & 1) * 64;
  int lr = lane & 15, lk = lane >> 4;
  stage4(A, aBase, aStr, 0, sA0, w, lane);
  stage4(B, bBase, bStr, 0, sB0, w, lane);
  int NT = K >> 6;
  for (int t = 0; t < NT; ++t) {
    u16* cA = (t & 1) ? sA1 : sA0;
    u16* cB = (t & 1) ? sB1 : sB0;
    if (t + 1 < NT) {
      u16* nA = (t & 1) ? sA0 : sA1;
      u16* nB = (t & 1) ? sB0 : sB1;
      stage4(A, aBase, aStr, (t + 1) << 6, nA, w, lane);
      stage4(B, bBase, bStr, (t + 1) << 6, nB, w, lane);
      asm volatile("s_waitcnt vmcnt(8)" ::: "memory");  // tile-t loads done, 8 in flight
    } else {
      asm volatile("s_waitcnt vmcnt(0)" ::: "memory");
    }
    __builtin_amdgcn_s_barrier();          // all waves: tile-t data resident
    __builtin_amdgcn_sched_barrier(0);
    bfx8 a[8], b[8];
#pragma unroll
    for (int h = 0; h < 2; ++h)
#pragma unroll
      for (int i = 0; i < 4; ++i) {
        a[h * 4 + i] = ldsw(cA, wm + i * 16 + lr, h * 4 + lk);
        b[h * 4 + i] = ldsw(cB, wn + i * 16 + lr, h * 4 + lk);
      }
    asm volatile("s_waitcnt lgkmcnt(0)" ::: "memory");  // reads complete (values in regs)
    __builtin_amdgcn_sched_barrier(0);
    __builtin_amdgcn_s_barrier();          // WAR: safe to restage this buffer next iter
#pragma unroll
    for (int h = 0; h < 2; ++h)
#pragma unroll
      for (int mi = 0; mi < 4; ++mi)
#pragma unroll
        for (int ni = 0; ni < 4; ++ni)
          acc[mi][ni] = mfma16(a[h * 4 + mi], b[h * 4 + ni], acc[mi][ni]);
  }
}

// ---- K0a: rope cos/sin tables. y=0: tabTI[t][i]; y=1: tabIT[i][t]. float2(cos,sin).
__global__ void k_ropetab(float2* __restrict__ tabTI, float2* __restrict__ tabIT) {
  int idx = blockIdx.x * 256 + threadIdx.x;  // 1M entries
  int t, i;
  if (blockIdx.y == 0) {
    t = idx >> 9;
    i = idx & 511;
  } else {
    i = idx >> 11;
    t = idx & 2047;
  }
  float invf = exp2f(-(float)i * (13.287712379549449f / 512.f));  // 10000^(-i/512)
  float ang = (float)t * invf, s, c;
  sincosf(ang, &s, &c);
  if (blockIdx.y == 0)
    tabTI[idx] = make_float2(c, s);
  else
    tabIT[idx] = make_float2(c, s);
}

// ---- K0b: transpose W (1024x3072 f32) -> WT[3072][1024] bf16
__global__ void k_transW(const float* __restrict__ W, u16* __restrict__ WTh) {
  __shared__ float tile[32][33];
  int n0 = blockIdx.x * 32, k0 = blockIdx.y * 32;
  int tid = threadIdx.x;
  int c = tid & 31, r4 = tid >> 5;
#pragma unroll
  for (int it = 0; it < 4; ++it) {
    int r = r4 + it * 8;
    tile[r][c] = W[(size_t)(k0 + r) * 3072 + n0 + c];
  }
  __syncthreads();
#pragma unroll
  for (int it = 0; it < 4; ++it) {
    int r = r4 + it * 8;
    WTh[(size_t)(n0 + r) * 1024 + k0 + c] = f2bh(tile[c][r]);
  }
}

// ---- K0c: cast x -> bf16 (8 elems/thread)
__global__ void k_castX(const float* __restrict__ x, u16* __restrict__ xh) {
  size_t i = ((size_t)blockIdx.x * 256 + threadIdx.x) * 8;
  fx4 v0 = *reinterpret_cast<const fx4*>(x + i);
  fx4 v1 = *reinterpret_cast<const fx4*>(x + i + 4);
  u16x8 h;
#pragma unroll
  for (int j = 0; j < 4; ++j) {
    h[j] = f2bh(v0[j]);
    h[4 + j] = f2bh(v1[j]);
  }
  *reinterpret_cast<u16x8*>(xh + i) = h;
}

// ---- G1 fused: relu(rope(x@W+b)) -> Qh row-major, Kth/Vth transposed [B][D][T]
__global__ __launch_bounds__(256) void k_gemm1f(const u16* __restrict__ xh,
                                                const u16* __restrict__ WTh,
                                                const float* __restrict__ b_in,
                                                const float2* __restrict__ tabTI,
                                                const float2* __restrict__ tabIT,
                                                u16* __restrict__ Qh, u16* __restrict__ Kth,
                                                u16* __restrict__ Vth) {
  __shared__ __align__(16) float shbuf[128 * TP];  // 66KB; 4x16KB staging buffers alias it
  u16* sA0 = (u16*)shbuf;
  u16* sB0 = sA0 + 128 * 64;
  u16* sA1 = sB0 + 128 * 64;
  u16* sB1 = sA1 + 128 * 64;
  // XCD-chunked swizzle: 1536 blocks = 8 XCD x (8 mt x 24 nt), mt-fastest within chunk.
  // Per-XCD A slice = 8x128 rows x 2KB = 2MB (L2-resident); B panels shared in time.
  int bid = blockIdx.x;
  int xcd = bid & 7, idx = bid >> 3;
  int mt = (xcd << 3) + (idx & 7), nt = idx >> 3;
  int m0 = mt << 7, n0 = nt << 7;
  int tid = threadIdx.x, lane = tid & 63, w = tid >> 6;
  int wm = (w >> 1) * 64, wn = (w & 1) * 64;
  int lr = lane & 15, lk = lane >> 4;
  fx4 acc[4][4];
#pragma unroll
  for (int i = 0; i < 4; ++i)
#pragma unroll
    for (int j = 0; j < 4; ++j) acc[i][j] = fx4{0.f, 0.f, 0.f, 0.f};

  gemm_core_pipe(xh, (size_t)m0, 1024, WTh, (size_t)n0, 1024, 1024,
                 sA0, sB0, sA1, sB1, acc, w, lane);

  // ---- Epilogue: acc+bias -> f32 LDS tile, then store in output order with
  // vectorized u16x8 stores + table-based rope.
  float bv[4];
#pragma unroll
  for (int ni = 0; ni < 4; ++ni) bv[ni] = b_in[n0 + wn + ni * 16 + lr];
  __syncthreads();  // all LDS reads of staging done before overwrite
#pragma unroll
  for (int mi = 0; mi < 4; ++mi)
#pragma unroll
    for (int ni = 0; ni < 4; ++ni)
#pragma unroll
      for (int r = 0; r < 4; ++r)
        shbuf[(wn + ni * 16 + lr) * TP + wm + mi * 16 + lk * 4 + r] = acc[mi][ni][r] + bv[ni];
  __syncthreads();

  int part = n0 >> 10;       // 0=Q, 1=K, 2=V (uniform per block)
  int d0 = n0 - (part << 10);
  int bb = m0 >> 11, tb = m0 & 2047;  // 128-row tiles never cross batch boundary
  int rl0 = tid >> 4;        // row within tile (per pass: +16)
  int cc = (tid & 15) * 8;   // 8-elem column chunk

  if (part == 2) {           // V: relu only, store [d][t]
#pragma unroll
    for (int pass = 0; pass < 8; ++pass) {
      int rl = rl0 + pass * 16;
      u16x8 o;
#pragma unroll
      for (int j = 0; j < 8; ++j) o[j] = f2bh(fmaxf(shbuf[rl * TP + cc + j], 0.f));
      *reinterpret_cast<u16x8*>(Vth + (((size_t)(bb << 10) + d0 + rl) << 11) + tb + cc) = o;
    }
  } else if (part == 1) {    // K: rope (rows d, d^1) + relu, store [d][t]
#pragma unroll
    for (int pass = 0; pass < 8; ++pass) {
      int rl = rl0 + pass * 16;
      int d = d0 + rl;
      const float2* tp = tabIT + ((size_t)(d >> 1) << 11) + tb + cc;
      const float* e = shbuf + (rl & ~1) * TP + cc;   // even row
      const float* oo = shbuf + (rl | 1) * TP + cc;   // odd row
      int isOdd = d & 1;
      u16x8 o;
#pragma unroll
      for (int j = 0; j < 8; ++j) {
        float2 cs = tp[j];
        float x1 = e[j], x2 = oo[j];
        float v = isOdd ? (x1 * cs.y + x2 * cs.x) : (x1 * cs.x - x2 * cs.y);
        o[j] = f2bh(fmaxf(v, 0.f));
      }
      *reinterpret_cast<u16x8*>(Kth + (((size_t)(bb << 10) + d) << 11) + tb + cc) = o;
    }
  } else {                   // Q: rope along d, store [m][d]
#pragma unroll
    for (int pass = 0; pass < 8; ++pass) {
      int rl = rl0 + pass * 16;  // m_local
      int m = m0 + rl, t = m & 2047;
      const float2* tp = tabTI + ((size_t)t << 9) + ((d0 + cc) >> 1);
      u16x8 o;
#pragma unroll
      for (int jp = 0; jp < 4; ++jp) {
        float x1 = shbuf[(cc + 2 * jp) * TP + rl];
        float x2 = shbuf[(cc + 2 * jp + 1) * TP + rl];
        float2 cs = tp[jp];
        o[2 * jp] = f2bh(fmaxf(x1 * cs.x - x2 * cs.y, 0.f));
        o[2 * jp + 1] = f2bh(fmaxf(x1 * cs.y + x2 * cs.x, 0.f));
      }
      *reinterpret_cast<u16x8*>(Qh + ((size_t)m << 10) + d0 + cc) = o;
    }
  }
}

// ---- G2: KtVT[b][n][m] = (K^T V)[m][n], bf16 out
__global__ __launch_bounds__(256) void k_gemm2(const u16* __restrict__ Kth, const u16* __restrict__ Vth,
                                               u16* __restrict__ KtVTh) {
  __shared__ u16 smem[4 * 128 * 64];
  u16* sA0 = smem;
  u16* sB0 = sA0 + 128 * 64;
  u16* sA1 = sB0 + 128 * 64;
  u16* sB1 = sA1 + 128 * 64;
  fx4 acc[4][4];
#pragma unroll
  for (int i = 0; i < 4; ++i)
#pragma unroll
    for (int j = 0; j < 4; ++j) acc[i][j] = fx4{0.f, 0.f, 0.f, 0.f};
  int b = blockIdx.z;
  int m0 = blockIdx.x << 7, n0 = blockIdx.y << 7;
  int tid = threadIdx.x, lane = tid & 63, w = tid >> 6;
  const u16* Ab = Kth + ((size_t)b << 21);
  const u16* Bb = Vth + ((size_t)b << 21);
  gemm_core_pipe(Ab, (size_t)m0, 2048, Bb, (size_t)n0, 2048, 2048,
                 sA0, sB0, sA1, sB1, acc, w, lane);
  int wm = (w >> 1) * 64, wn = (w & 1) * 64, lr = lane & 15, lk = lane >> 4;
#pragma unroll
  for (int mi = 0; mi < 4; ++mi)
#pragma unroll
    for (int ni = 0; ni < 4; ++ni)
#pragma unroll
      for (int r = 0; r < 4; ++r) {
        int m = m0 + wm + mi * 16 + lk * 4 + r;
        int n = n0 + wn + ni * 16 + lr;
        KtVTh[((size_t)b << 20) + ((size_t)n << 10) + m] = f2bh(acc[mi][ni][r]);
      }
}

// ---- G3 fused: y = Q @ KtV, then GroupNorm(32-ch groups) + transposed store out[b][d][t].
__global__ __launch_bounds__(256) void k_gemm3g(const u16* __restrict__ Qh, const u16* __restrict__ KtVTh,
                                                const float* __restrict__ gw, const float* __restrict__ gb,
                                                float* __restrict__ out) {
  __shared__ u16 smem[4 * 128 * 64];
  u16* sA0 = smem;
  u16* sB0 = sA0 + 128 * 64;
  u16* sA1 = sB0 + 128 * 64;
  u16* sB1 = sA1 + 128 * 64;
  fx4 acc[4][4];
#pragma unroll
  for (int i = 0; i < 4; ++i)
#pragma unroll
    for (int j = 0; j < 4; ++j) acc[i][j] = fx4{0.f, 0.f, 0.f, 0.f};
  int b = blockIdx.z;
  int m0 = blockIdx.x << 7, n0 = blockIdx.y << 7;
  int tid = threadIdx.x, lane = tid & 63, w = tid >> 6;
  gemm_core_pipe(Qh, (size_t)(b * 2048 + m0), 1024, KtVTh + ((size_t)b << 20), (size_t)n0, 1024,
                 1024, sA0, sB0, sA1, sB1, acc, w, lane);
  int wm = (w >> 1) * 64, wn = (w & 1) * 64, lr = lane & 15, lk = lane >> 4;
  float wv[4], bvv[4];
#pragma unroll
  for (int ni = 0; ni < 4; ++ni) {
    int n = n0 + wn + ni * 16 + lr;
    wv[ni] = gw[n];
    bvv[ni] = gb[n];
  }
#pragma unroll
  for (int mi = 0; mi < 4; ++mi) {
    fx4 o0, o1, o2, o3;
#pragma unroll
    for (int r = 0; r < 4; ++r) {
      float v0 = acc[mi][0][r], v1 = acc[mi][1][r], v2 = acc[mi][2][r], v3 = acc[mi][3][r];
      float sA2 = v0 + v1, sB2 = v2 + v3;
#pragma unroll
      for (int mk = 1; mk <= 8; mk <<= 1) {
        sA2 += __shfl_xor(sA2, mk);
        sB2 += __shfl_xor(sB2, mk);
      }
      float mA = sA2 * (1.f / 32.f), mB = sB2 * (1.f / 32.f);
      float dA = (v0 - mA) * (v0 - mA) + (v1 - mA) * (v1 - mA);
      float dB = (v2 - mB) * (v2 - mB) + (v3 - mB) * (v3 - mB);
#pragma unroll
      for (int mk = 1; mk <= 8; mk <<= 1) {
        dA += __shfl_xor(dA, mk);
        dB += __shfl_xor(dB, mk);
      }
      float rA = rsqrtf(dA * (1.f / 32.f) + 1e-5f);
      float rB = rsqrtf(dB * (1.f / 32.f) + 1e-5f);
      o0[r] = (v0 - mA) * rA * wv[0] + bvv[0];
      o1[r] = (v1 - mA) * rA * wv[1] + bvv[1];
      o2[r] = (v2 - mB) * rB * wv[2] + bvv[2];
      o3[r] = (v3 - mB) * rB * wv[3] + bvv[3];
    }
    int mbase = m0 + wm + mi * 16 + lk * 4;  // t index, 16B-aligned
#pragma unroll
    for (int ni = 0; ni < 4; ++ni) {
      int n = n0 + wn + ni * 16 + lr;
      fx4 ov = (ni == 0) ? o0 : (ni == 1) ? o1 : (ni == 2) ? o2 : o3;
      *reinterpret_cast<fx4*>(out + (((size_t)(b << 10) + n) << 11) + mbase) = ov;
    }
  }
}

extern "C" void kernel_launch(void* const* d_in, const int* in_sizes, int n_in,
                              void* d_out, int out_size, void* d_ws, size_t ws_size,
                              hipStream_t stream) {
  const float* x = (const float*)d_in[0];
  const float* W = (const float*)d_in[1];
  const float* b_in = (const float*)d_in[2];
  const float* gnw = (const float*)d_in[3];
  const float* gnb = (const float*)d_in[4];
  float* out = (float*)d_out;
  char* ws = (char*)d_ws;

  // Workspace (bytes): xh@0(16M) WTh@16M(6M) Qh@22M(16M) Kth@38M(16M) Vth@54M(16M)
  // KtVTh@70M(8M) tabTI@78M(8M) tabIT@86M(8M). Total ~94MB.
  u16* xh = (u16*)(ws + 0);
  u16* WTh = (u16*)(ws + 16777216);
  u16* Qh = (u16*)(ws + 23068672);
  u16* Kth = (u16*)(ws + 39845888);
  u16* Vth = (u16*)(ws + 56623104);
  u16* KtVTh = (u16*)(ws + 73400320);
  float2* tabTI = (float2*)(ws + 81788928);
  float2* tabIT = (float2*)(ws + 90177536);

  k_ropetab<<<dim3(4096, 2), 256, 0, stream>>>(tabTI, tabIT);
  k_transW<<<dim3(96, 32), 256, 0, stream>>>(W, WTh);
  k_castX<<<4096, 256, 0, stream>>>(x, xh);
  k_gemm1f<<<1536, 256, 0, stream>>>(xh, WTh, b_in, tabTI, tabIT, Qh, Kth, Vth);
  k_gemm2<<<dim3(8, 8, 4), 256, 0, stream>>>(Kth, Vth, KtVTh);
  k_gemm3g<<<dim3(16, 8, 4), 256, 0, stream>>>(Qh, KtVTh, gnw, gnb, out);
}